// Round 2
// baseline (1291.891 us; speedup 1.0000x reference)
//
#include <hip/hip_runtime.h>
#include <math.h>

// ---------------- problem dims ----------------
#define B_   32
#define I_   2048
#define J_   16
#define C_   64
#define D_   32
#define CD_  2048           // C_*D_ "columns"
#define W_CSTR (I_*D_*J_)   // 1048576 floats
#define W_ISTR (D_*J_)      // 512 floats
#define X_BSTR (I_*J_)      // 32768 floats
#define EPS_ 1e-7f

// Streaming-kernel thread mapping (shared by passA / blogit / passB2):
//   grid (64 i-chunks of 32, 8 col-eighths of 256), 512 threads.
//   bg = t>>6 (wave index, 4 consecutive b), colid = t&63 (4 consecutive cols
//   = 4 consecutive d within one c). W reads: lane colid -> 64 consecutive
//   floats => wave = 4 KB contiguous, perfectly coalesced. x reads are
//   wave-uniform (L1 broadcast). NO LDS, NO barriers -> waves free-run.
//   launch_bounds(512,4): VGPR<=128 => 2 blocks/CU = 16 waves/CU.

__device__ __forceinline__ float dot8(float4 w0, float4 w1, float4 x0, float4 x1) {
  return w0.x*x0.x + w0.y*x0.y + w0.z*x0.z + w0.w*x0.w
       + w1.x*x1.x + w1.y*x1.y + w1.z*x1.z + w1.w*x1.w;
}

// ================= K1: pass A =================
// part[ic][b][col] = sum_{i in chunk} sum_j x[b,i,j]*W[c,i,d,j], col=c*32+d
__global__ __launch_bounds__(512, 4) void k_passA(const float* __restrict__ x,
                                                  const float* __restrict__ W,
                                                  float* __restrict__ part) {
  const int t     = threadIdx.x;
  const int ic    = blockIdx.x;        // 0..63
  const int q8    = blockIdx.y;        // 0..7
  const int bg    = t >> 6;            // 0..7 (wave-uniform)
  const int colid = t & 63;
  const int col0  = q8*256 + colid*4;
  const int c     = col0 >> 5;
  const int d0    = col0 & 31;

  const float* wbase = W + (size_t)c*W_CSTR + d0*J_;
  const float* xbase = x + (size_t)(bg*4)*X_BSTR;

  float acc[4][4];
  #pragma unroll
  for (int a = 0; a < 4; a++)
    #pragma unroll
    for (int dd = 0; dd < 4; dd++) acc[a][dd] = 0.f;

  for (int ii = 0; ii < 32; ii++) {
    const int i = ic*32 + ii;
    const float* wp = wbase + (size_t)i*W_ISTR;
    const float* xp = xbase + (size_t)i*J_;
    #pragma unroll 1
    for (int jh = 0; jh < 2; jh++) {
      float4 wv[4][2];
      #pragma unroll
      for (int dd = 0; dd < 4; dd++) {
        wv[dd][0] = *(const float4*)(wp + dd*J_ + jh*8);
        wv[dd][1] = *(const float4*)(wp + dd*J_ + jh*8 + 4);
      }
      #pragma unroll
      for (int a = 0; a < 4; a++) {
        float4 x0 = *(const float4*)(xp + (size_t)a*X_BSTR + jh*8);
        float4 x1 = *(const float4*)(xp + (size_t)a*X_BSTR + jh*8 + 4);
        #pragma unroll
        for (int dd = 0; dd < 4; dd++)
          acc[a][dd] += dot8(wv[dd][0], wv[dd][1], x0, x1);
      }
    }
  }
  #pragma unroll
  for (int a = 0; a < 4; a++) {
    const int b = bg*4 + a;
    float4 st = make_float4(acc[a][0], acc[a][1], acc[a][2], acc[a][3]);
    *(float4*)(part + (size_t)ic*(B_*CD_) + (size_t)b*CD_ + col0) = st;
  }
}

// ================= K: b-logit pass =================
// b1[i][b][c] = sum_d v1[b,c,d] * u_hat[b,c,i,d], u_hat recomputed from W,x.
// Thread covers 4 d of one c; d-reduction over the 8-lane group via shfl_xor.
__global__ __launch_bounds__(512, 4) void k_blogit(const float* __restrict__ x,
                                                   const float* __restrict__ W,
                                                   const float* __restrict__ v1,
                                                   float* __restrict__ b1) {
  const int t     = threadIdx.x;
  const int ic    = blockIdx.x;
  const int q8    = blockIdx.y;
  const int bg    = t >> 6;
  const int colid = t & 63;
  const int col0  = q8*256 + colid*4;
  const int c     = col0 >> 5;
  const int d0    = col0 & 31;

  const float* wbase = W + (size_t)c*W_CSTR + d0*J_;
  const float* xbase = x + (size_t)(bg*4)*X_BSTR;

  float v1v[4][4];                       // [a][dd], loaded once
  #pragma unroll
  for (int a = 0; a < 4; a++)
    #pragma unroll
    for (int dd = 0; dd < 4; dd++)
      v1v[a][dd] = v1[(size_t)((bg*4 + a)*64 + c)*32 + d0 + dd];

  for (int ii = 0; ii < 32; ii++) {
    const int i = ic*32 + ii;
    const float* wp = wbase + (size_t)i*W_ISTR;
    const float* xp = xbase + (size_t)i*J_;

    float u[4][4];
    #pragma unroll
    for (int a = 0; a < 4; a++)
      #pragma unroll
      for (int dd = 0; dd < 4; dd++) u[a][dd] = 0.f;

    #pragma unroll 1
    for (int jh = 0; jh < 2; jh++) {
      float4 wv[4][2];
      #pragma unroll
      for (int dd = 0; dd < 4; dd++) {
        wv[dd][0] = *(const float4*)(wp + dd*J_ + jh*8);
        wv[dd][1] = *(const float4*)(wp + dd*J_ + jh*8 + 4);
      }
      #pragma unroll
      for (int a = 0; a < 4; a++) {
        float4 x0 = *(const float4*)(xp + (size_t)a*X_BSTR + jh*8);
        float4 x1 = *(const float4*)(xp + (size_t)a*X_BSTR + jh*8 + 4);
        #pragma unroll
        for (int dd = 0; dd < 4; dd++)
          u[a][dd] += dot8(wv[dd][0], wv[dd][1], x0, x1);
      }
    }

    #pragma unroll
    for (int a = 0; a < 4; a++) {
      float p = v1v[a][0]*u[a][0] + v1v[a][1]*u[a][1]
              + v1v[a][2]*u[a][2] + v1v[a][3]*u[a][3];
      p += __shfl_xor(p, 1);
      p += __shfl_xor(p, 2);
      p += __shfl_xor(p, 4);             // sum over the 8 d-groups of this c
      if ((colid & 7) == 0) {
        const int b = bg*4 + a;
        b1[(size_t)(i*B_ + b)*C_ + c] = p;
      }
    }
  }
}

// ================= K: softmax over c (rows of 64) =================
__global__ void k_softmax(const float* __restrict__ b1, float* __restrict__ c2) {
  const int t    = threadIdx.x;
  const int row  = blockIdx.x*4 + (t >> 6);  // (i*32+b), 65536 rows
  const int lane = t & 63;
  float v = b1[(size_t)row*64 + lane];
  float m = v;
  #pragma unroll
  for (int off = 32; off > 0; off >>= 1) m = fmaxf(m, __shfl_xor(m, off));
  const float e = __expf(v - m);
  float s = e;
  #pragma unroll
  for (int off = 32; off > 0; off >>= 1) s += __shfl_xor(s, off);
  c2[(size_t)row*64 + lane] = e / s;
}

// ================= K: pass B2 (s2 partials) =================
__global__ __launch_bounds__(512, 4) void k_passB2(const float* __restrict__ x,
                                                   const float* __restrict__ W,
                                                   const float* __restrict__ c2,
                                                   float* __restrict__ part) {
  const int t     = threadIdx.x;
  const int ic    = blockIdx.x;
  const int q8    = blockIdx.y;
  const int bg    = t >> 6;
  const int colid = t & 63;
  const int col0  = q8*256 + colid*4;
  const int c     = col0 >> 5;
  const int d0    = col0 & 31;

  const float* wbase = W + (size_t)c*W_CSTR + d0*J_;
  const float* xbase = x + (size_t)(bg*4)*X_BSTR;

  float s2[4][4];
  #pragma unroll
  for (int a = 0; a < 4; a++)
    #pragma unroll
    for (int dd = 0; dd < 4; dd++) s2[a][dd] = 0.f;

  for (int ii = 0; ii < 32; ii++) {
    const int i = ic*32 + ii;
    const float* wp = wbase + (size_t)i*W_ISTR;
    const float* xp = xbase + (size_t)i*J_;

    float u[4][4];
    #pragma unroll
    for (int a = 0; a < 4; a++)
      #pragma unroll
      for (int dd = 0; dd < 4; dd++) u[a][dd] = 0.f;

    #pragma unroll 1
    for (int jh = 0; jh < 2; jh++) {
      float4 wv[4][2];
      #pragma unroll
      for (int dd = 0; dd < 4; dd++) {
        wv[dd][0] = *(const float4*)(wp + dd*J_ + jh*8);
        wv[dd][1] = *(const float4*)(wp + dd*J_ + jh*8 + 4);
      }
      #pragma unroll
      for (int a = 0; a < 4; a++) {
        float4 x0 = *(const float4*)(xp + (size_t)a*X_BSTR + jh*8);
        float4 x1 = *(const float4*)(xp + (size_t)a*X_BSTR + jh*8 + 4);
        #pragma unroll
        for (int dd = 0; dd < 4; dd++)
          u[a][dd] += dot8(wv[dd][0], wv[dd][1], x0, x1);
      }
    }

    #pragma unroll
    for (int a = 0; a < 4; a++) {
      const int b = bg*4 + a;
      const float cv = c2[(size_t)(i*B_ + b)*C_ + c];
      #pragma unroll
      for (int dd = 0; dd < 4; dd++) s2[a][dd] += cv * u[a][dd];
    }
  }

  #pragma unroll
  for (int a = 0; a < 4; a++) {
    const int b = bg*4 + a;
    float4 st = make_float4(s2[a][0], s2[a][1], s2[a][2], s2[a][3]);
    *(float4*)(part + (size_t)ic*(B_*CD_) + (size_t)b*CD_ + col0) = st;
  }
}

// ================= K: chunk reduction =================
__global__ void k_reduce(const float* __restrict__ part, float* __restrict__ sfull) {
  const int g = blockIdx.x*256 + threadIdx.x;     // 0..65535
  float s = 0.f;
  #pragma unroll 8
  for (int ch = 0; ch < 64; ch++) s += part[(size_t)ch*(B_*CD_) + g];
  sfull[g] = s;
}

// ================= K: squash =================
// writes [b][c][d] layout (used for both v1 and the final output)
__global__ void k_squash(const float* __restrict__ sfull, float* __restrict__ outp,
                         float scale) {
  const int g = blockIdx.x*256 + threadIdx.x;     // 0..2047 = b*64+c
  if (g >= 2048) return;
  float s[32]; float sn = 0.f;
  #pragma unroll
  for (int d = 0; d < 32; d++) {
    s[d] = sfull[(size_t)g*32 + d] * scale;
    sn += s[d]*s[d];
  }
  const float sc = sn / ((1.f + sn) * sqrtf(sn + EPS_));
  #pragma unroll
  for (int d = 0; d < 32; d++) outp[(size_t)g*32 + d] = s[d]*sc;
}

// ================= host =================
extern "C" void kernel_launch(void* const* d_in, const int* in_sizes, int n_in,
                              void* d_out, int out_size, void* d_ws, size_t ws_size,
                              hipStream_t stream) {
  (void)in_sizes; (void)n_in; (void)out_size; (void)ws_size;
  const float* x = (const float*)d_in[0];   // [32, 2048, 16] f32
  const float* W = (const float*)d_in[1];   // [64, 2048, 32, 16] f32
  float* out = (float*)d_out;               // [32, 64, 32] f32

  char* ws = (char*)d_ws;
  float* part  = (float*)(ws);                           // region0: 16 MB
  float* b1    = (float*)(ws);                           // region0 (aliases part)
  float* c2    = (float*)(ws + (size_t)16*1024*1024);    // region1: 16 MB
  float* sfull = (float*)(ws + (size_t)32*1024*1024);            // 256 KB
  float* v1    = (float*)(ws + (size_t)32*1024*1024 + 256*1024); // 256 KB
  // total workspace used: 32.5 MB (same footprint as round 1)

  // s0 partials (region0)
  k_passA<<<dim3(64, 8), 512, 0, stream>>>(x, W, part);
  k_reduce<<<256, 256, 0, stream>>>(part, sfull);
  k_squash<<<8, 256, 0, stream>>>(sfull, v1, 1.f/64.f);      // v1[b][c][d]
  // routing logits (region0, part is dead) -> softmax -> c2 (region1)
  k_blogit<<<dim3(64, 8), 512, 0, stream>>>(x, W, v1, b1);
  k_softmax<<<16384, 256, 0, stream>>>(b1, c2);
  // s2 partials (region0, b1 is dead)
  k_passB2<<<dim3(64, 8), 512, 0, stream>>>(x, W, c2, part);
  k_reduce<<<256, 256, 0, stream>>>(part, sfull);
  k_squash<<<8, 256, 0, stream>>>(sfull, out, 1.f);
}

// Round 3
// 548.891 us; speedup vs baseline: 2.3536x; 2.3536x over previous
//
#include <hip/hip_runtime.h>
#include <math.h>

// ---------------- problem dims ----------------
#define B_   32
#define I_   2048
#define J_   16
#define C_   64
#define D_   32
#define CD_  2048           // C_*D_ "columns"
#define W_CSTR (I_*D_*J_)   // 1048576 floats
#define W_ISTR (D_*J_)      // 512 floats
#define X_BSTR (I_*J_)      // 32768 floats
#define EPS_ 1e-7f

typedef _Float16 half8 __attribute__((ext_vector_type(8)));
typedef float    f32x16 __attribute__((ext_vector_type(16)));

// MFMA geometry (v_mfma_f32_32x32x16_f16):
//   A[m][k]: m = lane&31 (= batch b), k = (lane>>5)*8 + e  (8 f16/lane)
//   B[k][n]: n = lane&31 (= d),       k = (lane>>5)*8 + e
//   C/D:     col(n) = lane&31, row(m) = (r&3) + 8*(r>>2) + 4*(lane>>5)
// Any internal permutation of k cancels as long as A and B use the same
// e-ordering (k is contracted) — xpack and the W-frag builder both use plain
// e = j-offset order.

// W-fragment built straight from fp32 W[c][i][d][j]: lane reads d=(l&31) row,
// j = (l>>5)*8..+7 -> two float4 from a hot 2 KB slab (32 lines/instr, slab
// L1-resident for the 2nd instr). Converts RNE to f16.
__device__ __forceinline__ half8 wfrag_from_f32(const float* __restrict__ W,
                                                int c, int i, int l) {
  const float* wp = W + (size_t)c*W_CSTR + (size_t)i*W_ISTR
                      + (size_t)(l & 31)*J_ + ((l >> 5) << 3);
  float4 a = *(const float4*)wp;
  float4 b = *(const float4*)(wp + 4);
  half8 h;
  h[0]=(_Float16)a.x; h[1]=(_Float16)a.y; h[2]=(_Float16)a.z; h[3]=(_Float16)a.w;
  h[4]=(_Float16)b.x; h[5]=(_Float16)b.y; h[6]=(_Float16)b.z; h[7]=(_Float16)b.w;
  return h;
}

// ================= K0: pack x into A-fragment layout =================
// xh[i][lane][e] f16, e = j-offset:  element = x[b=lane&31][i][(lane>>5)*8+e]
__global__ __launch_bounds__(256) void k_xpack(const float* __restrict__ x,
                                               half8* __restrict__ xh) {
  const int tg = blockIdx.x*256 + threadIdx.x;    // 0..131071
  const int i = tg >> 6, l = tg & 63;
  const int b = l & 31, jb = (l >> 5) << 3;
  const float* xp = x + (size_t)b*X_BSTR + (size_t)i*J_ + jb;
  float4 a = *(const float4*)xp;
  float4 bb = *(const float4*)(xp + 4);
  half8 h;
  h[0]=(_Float16)a.x;  h[1]=(_Float16)a.y;  h[2]=(_Float16)a.z;  h[3]=(_Float16)a.w;
  h[4]=(_Float16)bb.x; h[5]=(_Float16)bb.y; h[6]=(_Float16)bb.z; h[7]=(_Float16)bb.w;
  xh[tg] = h;                                     // contiguous 16 B/thread
}

// ================= K1: pass A (s0 partials, + optional WB build) ========
// grid (64 ic, 8 cb) x 512: wave w -> c = cb*8+w; i-loop over chunk of 32.
// One MFMA per (c,i); C-regs accumulate s0 over the chunk.
template<bool WRITE_WB>
__global__ __launch_bounds__(512, 4) void k_passA(const float* __restrict__ W,
                                                  const half8* __restrict__ xh,
                                                  float* __restrict__ part,
                                                  _Float16* __restrict__ WB) {
  const int t = threadIdx.x, l = t & 63, w = t >> 6;
  const int ic = blockIdx.x, c = blockIdx.y*8 + w;
  f32x16 acc = {};
  #pragma unroll 2
  for (int ii = 0; ii < 32; ii++) {
    const int i = ic*32 + ii;
    half8 wf = wfrag_from_f32(W, c, i, l);
    half8 xf = xh[(size_t)i*64 + l];
    if (WRITE_WB)
      *(half8*)(WB + ((size_t)c*I_ + i)*512 + (size_t)l*8) = wf;  // 1 KB/wave contig
    acc = __builtin_amdgcn_mfma_f32_32x32x16_f16(xf, wf, acc, 0, 0, 0);
  }
  const int col = c*32 + (l & 31), h4 = (l >> 5)*4;
  #pragma unroll
  for (int r = 0; r < 16; r++) {
    const int row = (r & 3) + 8*(r >> 2) + h4;    // = b
    part[(size_t)ic*(B_*CD_) + (size_t)row*CD_ + col] = acc[r];
  }
}

// ================= K2: chunk reduction =================
__global__ void k_reduce(const float* __restrict__ part, float* __restrict__ sfull) {
  const int g = blockIdx.x*256 + threadIdx.x;     // 0..65535
  float s = 0.f;
  #pragma unroll 8
  for (int ch = 0; ch < 64; ch++) s += part[(size_t)ch*(B_*CD_) + g];
  sfull[g] = s;
}

// ================= K3: squash -> [b][c][d] fp32 =================
__global__ void k_squash(const float* __restrict__ sfull, float* __restrict__ outp,
                         float scale) {
  const int g = blockIdx.x*256 + threadIdx.x;     // 0..2047 = b*64+c
  if (g >= 2048) return;
  float s[32]; float sn = 0.f;
  #pragma unroll
  for (int d = 0; d < 32; d++) {
    s[d] = sfull[(size_t)g*32 + d] * scale;
    sn += s[d]*s[d];
  }
  const float sc = sn / ((1.f + sn) * sqrtf(sn + EPS_));
  #pragma unroll
  for (int d = 0; d < 32; d++) outp[(size_t)g*32 + d] = s[d]*sc;
}

// ================= K4: b-logits -> b1[i][c][b] =================
// u = MFMA; p[r] = v1[row(r),c,d]*u[r]; butterfly over the 32 cols of the
// half (xor 1..16); lane 0/32 writes 4 float4 (rows 8g+4h .. +3).
template<bool USE_WB>
__global__ __launch_bounds__(512, 4) void k_blogit(const float* __restrict__ W,
                                                   const _Float16* __restrict__ WB,
                                                   const half8* __restrict__ xh,
                                                   const float* __restrict__ v1,
                                                   float* __restrict__ b1) {
  const int t = threadIdx.x, l = t & 63, w = t >> 6;
  const int ic = blockIdx.x, c = blockIdx.y*8 + w;
  const int d = l & 31, h4 = (l >> 5)*4;

  float v1r[16];
  #pragma unroll
  for (int r = 0; r < 16; r++) {
    const int row = (r & 3) + 8*(r >> 2) + h4;
    v1r[r] = v1[((size_t)row*64 + c)*32 + d];
  }

  #pragma unroll 2
  for (int ii = 0; ii < 32; ii++) {
    const int i = ic*32 + ii;
    half8 wf = USE_WB ? *(const half8*)(WB + ((size_t)c*I_ + i)*512 + (size_t)l*8)
                      : wfrag_from_f32(W, c, i, l);
    half8 xf = xh[(size_t)i*64 + l];
    f32x16 z = {};
    f32x16 u = __builtin_amdgcn_mfma_f32_32x32x16_f16(xf, wf, z, 0, 0, 0);

    float p[16];
    #pragma unroll
    for (int r = 0; r < 16; r++) p[r] = v1r[r] * u[r];
    #pragma unroll
    for (int s = 1; s <= 16; s <<= 1) {
      #pragma unroll
      for (int r = 0; r < 16; r++) p[r] += __shfl_xor(p[r], s);
    }
    if ((l & 31) == 0) {
      float* dst = b1 + ((size_t)i*64 + c)*32 + h4;
      #pragma unroll
      for (int g = 0; g < 4; g++)
        *(float4*)(dst + 8*g) = make_float4(p[4*g], p[4*g+1], p[4*g+2], p[4*g+3]);
    }
  }
}

// ================= K5: softmax over c, [i][c][b] tiles =================
__global__ __launch_bounds__(256) void k_softmaxT(const float* __restrict__ b1,
                                                  float* __restrict__ c2) {
  __shared__ float ST[2048];
  __shared__ float inv[32];
  const int i = blockIdx.x, t = threadIdx.x;
  const float* src = b1 + (size_t)i*2048;
  *(float4*)(ST + t*8)     = *(const float4*)(src + t*8);
  *(float4*)(ST + t*8 + 4) = *(const float4*)(src + t*8 + 4);
  __syncthreads();
  if (t < 32) {                    // thread t owns column b=t (bank t: conflict-free)
    float m = -1e30f;
    for (int cc = 0; cc < 64; cc++) m = fmaxf(m, ST[cc*32 + t]);
    float s = 0.f;
    for (int cc = 0; cc < 64; cc++) {
      const float e = __expf(ST[cc*32 + t] - m);
      s += e;
      ST[cc*32 + t] = e;
    }
    inv[t] = 1.f / s;
  }
  __syncthreads();
  float* dst = c2 + (size_t)i*2048;
  #pragma unroll
  for (int k = 0; k < 2; k++) {
    const int base = t*8 + k*4;
    float4 v = *(const float4*)(ST + base);
    v.x *= inv[(base+0) & 31]; v.y *= inv[(base+1) & 31];
    v.z *= inv[(base+2) & 31]; v.w *= inv[(base+3) & 31];
    *(float4*)(dst + base) = v;
  }
}

// ================= K6: pass B2 (s2 partials) =================
// u = MFMA (fresh C); s2[r] += c2[i,row(r),c]*u[r]; c2 via 4 uniform float4
// loads (rows {8g+4h..+3} are contiguous & 16B-aligned in [i][c][b] layout).
template<bool USE_WB>
__global__ __launch_bounds__(512, 4) void k_passB2(const float* __restrict__ W,
                                                   const _Float16* __restrict__ WB,
                                                   const half8* __restrict__ xh,
                                                   const float* __restrict__ c2,
                                                   float* __restrict__ part) {
  const int t = threadIdx.x, l = t & 63, w = t >> 6;
  const int ic = blockIdx.x, c = blockIdx.y*8 + w;
  const int h4 = (l >> 5)*4;
  f32x16 s2 = {};
  #pragma unroll 2
  for (int ii = 0; ii < 32; ii++) {
    const int i = ic*32 + ii;
    half8 wf = USE_WB ? *(const half8*)(WB + ((size_t)c*I_ + i)*512 + (size_t)l*8)
                      : wfrag_from_f32(W, c, i, l);
    half8 xf = xh[(size_t)i*64 + l];
    f32x16 z = {};
    f32x16 u = __builtin_amdgcn_mfma_f32_32x32x16_f16(xf, wf, z, 0, 0, 0);
    const float* cp = c2 + ((size_t)i*64 + c)*32 + h4;
    float4 c0 = *(const float4*)(cp);
    float4 c1 = *(const float4*)(cp + 8);
    float4 cB = *(const float4*)(cp + 16);
    float4 c3 = *(const float4*)(cp + 24);
    s2[0] += c0.x*u[0];  s2[1] += c0.y*u[1];  s2[2]  += c0.z*u[2];  s2[3]  += c0.w*u[3];
    s2[4] += c1.x*u[4];  s2[5] += c1.y*u[5];  s2[6]  += c1.z*u[6];  s2[7]  += c1.w*u[7];
    s2[8] += cB.x*u[8];  s2[9] += cB.y*u[9];  s2[10] += cB.z*u[10]; s2[11] += cB.w*u[11];
    s2[12]+= c3.x*u[12]; s2[13]+= c3.y*u[13]; s2[14] += c3.z*u[14]; s2[15] += c3.w*u[15];
  }
  const int col = c*32 + (l & 31);
  #pragma unroll
  for (int r = 0; r < 16; r++) {
    const int row = (r & 3) + 8*(r >> 2) + h4;
    part[(size_t)ic*(B_*CD_) + (size_t)row*CD_ + col] = s2[r];
  }
}

// ================= host =================
extern "C" void kernel_launch(void* const* d_in, const int* in_sizes, int n_in,
                              void* d_out, int out_size, void* d_ws, size_t ws_size,
                              hipStream_t stream) {
  (void)in_sizes; (void)n_in; (void)out_size;
  const float* x = (const float*)d_in[0];   // [32, 2048, 16] f32
  const float* W = (const float*)d_in[1];   // [64, 2048, 32, 16] f32
  float* out = (float*)d_out;               // [32, 64, 32] f32

  const size_t MiB = 1024*1024;
  char* ws = (char*)d_ws;
  const bool big = ws_size >= 163*MiB;      // WB path needs ~162.5 MiB

  _Float16* WB; float *part, *b1, *c2, *xhp, *sfull, *v1;
  if (big) {
    WB    = (_Float16*)(ws);                //   128 MiB: f16 W fragments
    part  = (float*)(ws + 128*MiB);         //    16 MiB
    b1    = part;                           //    alias (sequential lifetime)
    c2    = (float*)(ws + 144*MiB);         //    16 MiB
    xhp   = (float*)(ws + 160*MiB);         //     2 MiB
    sfull = (float*)(ws + 162*MiB);         //   256 KiB
    v1    = (float*)(ws + 162*MiB + 256*1024);
  } else {
    WB    = nullptr;
    part  = (float*)(ws);
    b1    = part;
    c2    = (float*)(ws + 16*MiB);
    xhp   = (float*)(ws + 32*MiB);
    sfull = (float*)(ws + 34*MiB);
    v1    = (float*)(ws + 34*MiB + 256*1024);
  }
  half8* xh = (half8*)xhp;

  k_xpack<<<512, 256, 0, stream>>>(x, xh);
  if (big) k_passA<true ><<<dim3(64, 8), 512, 0, stream>>>(W, xh, part, WB);
  else     k_passA<false><<<dim3(64, 8), 512, 0, stream>>>(W, xh, part, WB);
  k_reduce<<<256, 256, 0, stream>>>(part, sfull);
  k_squash<<<8, 256, 0, stream>>>(sfull, v1, 1.f/64.f);     // v1[b][c][d]
  if (big) k_blogit<true ><<<dim3(64, 8), 512, 0, stream>>>(W, WB, xh, v1, b1);
  else     k_blogit<false><<<dim3(64, 8), 512, 0, stream>>>(W, WB, xh, v1, b1);
  k_softmaxT<<<2048, 256, 0, stream>>>(b1, c2);
  if (big) k_passB2<true ><<<dim3(64, 8), 512, 0, stream>>>(W, WB, xh, c2, part);
  else     k_passB2<false><<<dim3(64, 8), 512, 0, stream>>>(W, WB, xh, c2, part);
  k_reduce<<<256, 256, 0, stream>>>(part, sfull);
  k_squash<<<8, 256, 0, stream>>>(sfull, out, 1.f);
}

// Round 4
// 541.487 us; speedup vs baseline: 2.3858x; 1.0137x over previous
//
#include <hip/hip_runtime.h>
#include <math.h>

// ---------------- problem dims ----------------
#define B_   32
#define I_   2048
#define J_   16
#define C_   64
#define D_   32
#define CD_  2048           // C_*D_ "columns"
#define W_CSTR (I_*D_*J_)   // 1048576 floats
#define W_ISTR (D_*J_)      // 512 floats
#define X_BSTR (I_*J_)      // 32768 floats
#define EPS_ 1e-7f

typedef _Float16 half8 __attribute__((ext_vector_type(8)));
typedef float    f32x16 __attribute__((ext_vector_type(16)));

// MFMA geometry (v_mfma_f32_32x32x16_f16):
//   A[m][k]: m = lane&31 (= batch b), k = (lane>>5)*8 + e  (8 f16/lane)
//   B[k][n]: n = lane&31 (= d),       k = (lane>>5)*8 + e
//   C/D:     col(n) = lane&31, row(m) = (r&3) + 8*(r>>2) + 4*(lane>>5)

__device__ __forceinline__ half8 wfrag_from_f32(const float* __restrict__ W,
                                                int c, int i, int l) {
  const float* wp = W + (size_t)c*W_CSTR + (size_t)i*W_ISTR
                      + (size_t)(l & 31)*J_ + ((l >> 5) << 3);
  float4 a = *(const float4*)wp;
  float4 b = *(const float4*)(wp + 4);
  half8 h;
  h[0]=(_Float16)a.x; h[1]=(_Float16)a.y; h[2]=(_Float16)a.z; h[3]=(_Float16)a.w;
  h[4]=(_Float16)b.x; h[5]=(_Float16)b.y; h[6]=(_Float16)b.z; h[7]=(_Float16)b.w;
  return h;
}

// ================= K0: pack x into A-fragment layout =================
__global__ __launch_bounds__(256) void k_xpack(const float* __restrict__ x,
                                               half8* __restrict__ xh) {
  const int tg = blockIdx.x*256 + threadIdx.x;    // 0..131071
  const int i = tg >> 6, l = tg & 63;
  const int b = l & 31, jb = (l >> 5) << 3;
  const float* xp = x + (size_t)b*X_BSTR + (size_t)i*J_ + jb;
  float4 a = *(const float4*)xp;
  float4 bb = *(const float4*)(xp + 4);
  half8 h;
  h[0]=(_Float16)a.x;  h[1]=(_Float16)a.y;  h[2]=(_Float16)a.z;  h[3]=(_Float16)a.w;
  h[4]=(_Float16)bb.x; h[5]=(_Float16)bb.y; h[6]=(_Float16)bb.z; h[7]=(_Float16)bb.w;
  xh[tg] = h;
}

// ================= K1: pass A (s0 partials + WB build) =================
template<bool WRITE_WB>
__global__ __launch_bounds__(512, 4) void k_passA(const float* __restrict__ W,
                                                  const half8* __restrict__ xh,
                                                  float* __restrict__ part,
                                                  _Float16* __restrict__ WB) {
  const int t = threadIdx.x, l = t & 63, w = t >> 6;
  const int ic = blockIdx.x, c = blockIdx.y*8 + w;
  f32x16 acc = {};
  #pragma unroll 4
  for (int ii = 0; ii < 32; ii++) {
    const int i = ic*32 + ii;
    half8 wf = wfrag_from_f32(W, c, i, l);
    half8 xf = xh[(size_t)i*64 + l];
    if (WRITE_WB)
      *(half8*)(WB + ((size_t)c*I_ + i)*512 + (size_t)l*8) = wf;
    acc = __builtin_amdgcn_mfma_f32_32x32x16_f16(xf, wf, acc, 0, 0, 0);
  }
  const int col = c*32 + (l & 31), h4 = (l >> 5)*4;
  #pragma unroll
  for (int r = 0; r < 16; r++) {
    const int row = (r & 3) + 8*(r >> 2) + h4;    // = b
    part[(size_t)ic*(B_*CD_) + (size_t)row*CD_ + col] = acc[r];
  }
}

// ================= K2: fused chunk-reduce + squash =================
// g = b*2048 + c*32 + d; a (b,c) row = 32 consecutive g = 32-lane half-wave,
// so ||s||^2 is a 5-step xor-shuffle. Writes [b][c][d] fp32.
__global__ __launch_bounds__(256) void k_redsquash(const float* __restrict__ part,
                                                   float* __restrict__ outp,
                                                   float scale) {
  const int g = blockIdx.x*256 + threadIdx.x;     // 0..65535
  float s = 0.f;
  #pragma unroll 8
  for (int ch = 0; ch < 64; ch++) s += part[(size_t)ch*(B_*CD_) + g];
  s *= scale;
  float sn = s*s;
  #pragma unroll
  for (int off = 1; off <= 16; off <<= 1) sn += __shfl_xor(sn, off);
  const float sc = sn / ((1.f + sn) * sqrtf(sn + EPS_));
  outp[g] = s*sc;
}

// ================= K3: b-logits -> b1[i][c][b] =================
// Fold-reduce: xor16-add on 16 regs, cndmask-fold to 8/4/2/1 between stages.
// 31 shuffle-adds + 15 selects (vs 80+80 plain butterfly).
template<bool USE_WB>
__global__ __launch_bounds__(512, 4) void k_blogit(const float* __restrict__ W,
                                                   const _Float16* __restrict__ WB,
                                                   const half8* __restrict__ xh,
                                                   const float* __restrict__ v1,
                                                   float* __restrict__ b1) {
  const int t = threadIdx.x, l = t & 63, w = t >> 6;
  const int ic = blockIdx.x, c = blockIdx.y*8 + w;
  const int d = l & 31, h4 = (l >> 5)*4;

  float v1r[16];
  #pragma unroll
  for (int r = 0; r < 16; r++) {
    const int row = (r & 3) + 8*(r >> 2) + h4;
    v1r[r] = v1[((size_t)row*64 + c)*32 + d];
  }
  // output row for this lane after the folds (even lanes write):
  const int orow = (((l >> 4) & 1) ? 8 : 0) + (((l >> 3) & 1) ? 4 : 0)
                 + (((l >> 2) & 1) ? 2 : 0) + ((l >> 1) & 1);
  const int wrow = (orow & 3) + 8*(orow >> 2) + h4;

  const bool s4 = (l & 16), s3 = (l & 8), s2b = (l & 4), s1 = (l & 2);

  #pragma unroll 2
  for (int ii = 0; ii < 32; ii++) {
    const int i = ic*32 + ii;
    half8 wf = USE_WB ? *(const half8*)(WB + ((size_t)c*I_ + i)*512 + (size_t)l*8)
                      : wfrag_from_f32(W, c, i, l);
    half8 xf = xh[(size_t)i*64 + l];
    f32x16 z = {};
    f32x16 u = __builtin_amdgcn_mfma_f32_32x32x16_f16(xf, wf, z, 0, 0, 0);

    float p[16];
    #pragma unroll
    for (int r = 0; r < 16; r++) p[r] = v1r[r] * u[r];
    #pragma unroll
    for (int r = 0; r < 16; r++) p[r] += __shfl_xor(p[r], 16);
    float q[8];
    #pragma unroll
    for (int r = 0; r < 8; r++) q[r] = s4 ? p[r+8] : p[r];
    #pragma unroll
    for (int r = 0; r < 8; r++) q[r] += __shfl_xor(q[r], 8);
    float q4[4];
    #pragma unroll
    for (int r = 0; r < 4; r++) q4[r] = s3 ? q[r+4] : q[r];
    #pragma unroll
    for (int r = 0; r < 4; r++) q4[r] += __shfl_xor(q4[r], 4);
    float q2[2];
    #pragma unroll
    for (int r = 0; r < 2; r++) q2[r] = s2b ? q4[r+2] : q4[r];
    #pragma unroll
    for (int r = 0; r < 2; r++) q2[r] += __shfl_xor(q2[r], 2);
    float y = s1 ? q2[1] : q2[0];
    y += __shfl_xor(y, 1);

    if ((l & 1) == 0)
      b1[((size_t)i*64 + c)*32 + wrow] = y;
  }
}

// ================= K4: softmax over c, [i][c][b] tiles =================
// 256 threads: b = t&31, chunk = t>>5 covers 8 c's. LDS partial max/sum.
__global__ __launch_bounds__(256) void k_softmaxT(const float* __restrict__ b1,
                                                  float* __restrict__ c2) {
  __shared__ float ST[2048];
  __shared__ float PM[256], PS[256];
  const int i = blockIdx.x, t = threadIdx.x;
  const float* src = b1 + (size_t)i*2048;
  *(float4*)(ST + t*8)     = *(const float4*)(src + t*8);
  *(float4*)(ST + t*8 + 4) = *(const float4*)(src + t*8 + 4);
  __syncthreads();
  const int b = t & 31, ck = t >> 5;
  float m = -1e30f;
  #pragma unroll
  for (int cc = 0; cc < 8; cc++) m = fmaxf(m, ST[(ck*8 + cc)*32 + b]);
  PM[t] = m;
  __syncthreads();
  #pragma unroll
  for (int k = 0; k < 8; k++) m = fmaxf(m, PM[k*32 + b]);
  float s = 0.f;
  #pragma unroll
  for (int cc = 0; cc < 8; cc++) {
    const int idx = (ck*8 + cc)*32 + b;
    const float e = __expf(ST[idx] - m);
    s += e;
    ST[idx] = e;
  }
  PS[t] = s;
  __syncthreads();
  s = 0.f;
  #pragma unroll
  for (int k = 0; k < 8; k++) s += PS[k*32 + b];
  const float inv = 1.f / s;
  float* dst = c2 + (size_t)i*2048;
  #pragma unroll
  for (int cc = 0; cc < 8; cc++) {
    const int idx = (ck*8 + cc)*32 + b;
    dst[idx] = ST[idx] * inv;
  }
}

// ================= K5: pass B2 (s2 partials) =================
template<bool USE_WB>
__global__ __launch_bounds__(512, 4) void k_passB2(const float* __restrict__ W,
                                                   const _Float16* __restrict__ WB,
                                                   const half8* __restrict__ xh,
                                                   const float* __restrict__ c2,
                                                   float* __restrict__ part) {
  const int t = threadIdx.x, l = t & 63, w = t >> 6;
  const int ic = blockIdx.x, c = blockIdx.y*8 + w;
  const int h4 = (l >> 5)*4;
  f32x16 s2 = {};
  #pragma unroll 2
  for (int ii = 0; ii < 32; ii++) {
    const int i = ic*32 + ii;
    half8 wf = USE_WB ? *(const half8*)(WB + ((size_t)c*I_ + i)*512 + (size_t)l*8)
                      : wfrag_from_f32(W, c, i, l);
    half8 xf = xh[(size_t)i*64 + l];
    f32x16 z = {};
    f32x16 u = __builtin_amdgcn_mfma_f32_32x32x16_f16(xf, wf, z, 0, 0, 0);
    const float* cp = c2 + ((size_t)i*64 + c)*32 + h4;
    float4 c0 = *(const float4*)(cp);
    float4 c1 = *(const float4*)(cp + 8);
    float4 cB = *(const float4*)(cp + 16);
    float4 c3 = *(const float4*)(cp + 24);
    s2[0] += c0.x*u[0];  s2[1] += c0.y*u[1];  s2[2]  += c0.z*u[2];  s2[3]  += c0.w*u[3];
    s2[4] += c1.x*u[4];  s2[5] += c1.y*u[5];  s2[6]  += c1.z*u[6];  s2[7]  += c1.w*u[7];
    s2[8] += cB.x*u[8];  s2[9] += cB.y*u[9];  s2[10] += cB.z*u[10]; s2[11] += cB.w*u[11];
    s2[12]+= c3.x*u[12]; s2[13]+= c3.y*u[13]; s2[14] += c3.z*u[14]; s2[15] += c3.w*u[15];
  }
  const int col = c*32 + (l & 31);
  #pragma unroll
  for (int r = 0; r < 16; r++) {
    const int row = (r & 3) + 8*(r >> 2) + h4;
    part[(size_t)ic*(B_*CD_) + (size_t)row*CD_ + col] = s2[r];
  }
}

// ================= host =================
extern "C" void kernel_launch(void* const* d_in, const int* in_sizes, int n_in,
                              void* d_out, int out_size, void* d_ws, size_t ws_size,
                              hipStream_t stream) {
  (void)in_sizes; (void)n_in; (void)out_size;
  const float* x = (const float*)d_in[0];   // [32, 2048, 16] f32
  const float* W = (const float*)d_in[1];   // [64, 2048, 32, 16] f32
  float* out = (float*)d_out;               // [32, 64, 32] f32

  const size_t MiB = 1024*1024;
  char* ws = (char*)d_ws;
  const bool big = ws_size >= 163*MiB;

  _Float16* WB; float *part, *b1, *c2, *xhp, *v1;
  if (big) {
    WB    = (_Float16*)(ws);                //   128 MiB f16 W fragments
    part  = (float*)(ws + 128*MiB);         //    16 MiB
    b1    = part;                           //    alias (sequential lifetime)
    c2    = (float*)(ws + 144*MiB);         //    16 MiB
    xhp   = (float*)(ws + 160*MiB);         //     2 MiB
    v1    = (float*)(ws + 162*MiB);         //   256 KiB
  } else {
    WB    = nullptr;
    part  = (float*)(ws);
    b1    = part;
    c2    = (float*)(ws + 16*MiB);
    xhp   = (float*)(ws + 32*MiB);
    v1    = (float*)(ws + 34*MiB);
  }
  half8* xh = (half8*)xhp;

  k_xpack<<<512, 256, 0, stream>>>(x, xh);
  if (big) k_passA<true ><<<dim3(64, 8), 512, 0, stream>>>(W, xh, part, WB);
  else     k_passA<false><<<dim3(64, 8), 512, 0, stream>>>(W, xh, part, WB);
  k_redsquash<<<256, 256, 0, stream>>>(part, v1, 1.f/64.f);   // v1[b][c][d]
  if (big) k_blogit<true ><<<dim3(64, 8), 512, 0, stream>>>(W, WB, xh, v1, b1);
  else     k_blogit<false><<<dim3(64, 8), 512, 0, stream>>>(W, WB, xh, v1, b1);
  k_softmaxT<<<2048, 256, 0, stream>>>(b1, c2);
  if (big) k_passB2<true ><<<dim3(64, 8), 512, 0, stream>>>(W, WB, xh, c2, part);
  else     k_passB2<false><<<dim3(64, 8), 512, 0, stream>>>(W, WB, xh, c2, part);
  k_redsquash<<<256, 256, 0, stream>>>(part, out, 1.f);
}